// Round 2
// baseline (2714.288 us; speedup 1.0000x reference)
//
#include <hip/hip_runtime.h>
#include <math.h>
#include <stdint.h>

typedef __bf16 bf16_t;
typedef __bf16 bf16x8 __attribute__((ext_vector_type(8)));
typedef __bf16 bf16x4 __attribute__((ext_vector_type(4)));
typedef float f32x4 __attribute__((ext_vector_type(4)));

#define NLAYER 6
#define DMODEL 768
#define NHEAD 12
#define DHEAD 64
#define SEQ 512
#define BATCH 8
#define MROWS 4096 /* BATCH*SEQ */
#define DFFN 3072

// ---------- helpers ----------

__device__ inline void async_load16(const void* g, void* lds) {
  const __attribute__((address_space(1))) void* gp =
      (const __attribute__((address_space(1))) void*)(uintptr_t)g;
  __attribute__((address_space(3))) void* lp =
      (__attribute__((address_space(3))) void*)(uint32_t)(uintptr_t)lds;
  __builtin_amdgcn_global_load_lds(gp, lp, 16, 0, 0);
}

#define VMCNT(n) __builtin_amdgcn_s_waitcnt(0x0F70 | (n))

__device__ inline float wsum(float v) {
#pragma unroll
  for (int o = 32; o > 0; o >>= 1) v += __shfl_xor(v, o, 64);
  return v;
}

__device__ inline float gelu_f(float x) {
  float u = 0.7978845608028654f * (x + 0.044715f * x * x * x);
  return 0.5f * x * (1.0f + tanhf(u));
}

// ---------- GEMM:  C[m,n] = sum_k A[m,k] * B[n,k]  (B is [N,K] row-major) ----------
// 256x256 tile, BK=64, 512 threads (8 waves, 2Mx4N). 8-phase schedule over
// K-HALF regions: per buffer {A.kh0, A.kh1, B.kh0, B.kh1}, each 256x32 bf16
// (16KB, LDS-contiguous). Each region's last read is <=1 phase after first
// use, so it is re-staged immediately and lands 6-7 phases before its next
// read. Uniform trailing vmcnt(10) per phase (2 loads/phase, 5 phases in
// flight) -- loads are NEVER waited on sooner than 5 phases after issue.
// XOR swizzle within a region: data slot kq (of 4 x 8-elem slots per row)
// stored at slot kq ^ ((row>>1)&3); staging pre-swizzles the global source
// column so global_load_lds' linear dest matches (both-sides rule).
struct GP {
  const bf16_t* A;
  const bf16_t* B;
  const float* bias;   // [N] or null (ignored when ksplit>1)
  const float* resid;  // f32, ldc layout, or null
  float* outF;         // f32 out (or partial base when ksplit>1)
  bf16_t* outB;        // bf16 out or null
  int M, N, K;
  int lda, ldb, ldc;
  long pstride;  // partial-buffer stride (elements) for ksplit>1
  int act;       // 1 = gelu
  int ksplit;
};

// one phase: 4 (+4) ds_read_b128, 1 region stage (2 global_load_lds),
// barrier, 16 MFMA, vmcnt(10), barrier.
#define PHASE(d, kk, mb, LOADB, STAGE)                                        \
  do {                                                                        \
    bf16x8 a_[4];                                                             \
    _Pragma("unroll") for (int i_ = 0; i_ < 4; ++i_) a_[i_] =                 \
        ldA(d, kk, (mb) + i_);                                                \
    if (LOADB) {                                                              \
      _Pragma("unroll") for (int j_ = 0; j_ < 4; ++j_) bfr[j_] =              \
          ldB(d, kk, j_);                                                     \
    }                                                                         \
    STAGE;                                                                    \
    __builtin_amdgcn_s_barrier();                                             \
    __builtin_amdgcn_s_setprio(1);                                            \
    _Pragma("unroll") for (int i_ = 0; i_ < 4; ++i_)                          \
        _Pragma("unroll") for (int j_ = 0; j_ < 4; ++j_) acc[(mb) + i_][j_] = \
            __builtin_amdgcn_mfma_f32_16x16x32_bf16(a_[i_], bfr[j_],          \
                                                    acc[(mb) + i_][j_], 0, 0, \
                                                    0);                       \
    __builtin_amdgcn_s_setprio(0);                                            \
    VMCNT(10);                                                                \
    __builtin_amdgcn_sched_barrier(0);                                        \
    __builtin_amdgcn_s_barrier();                                             \
    __builtin_amdgcn_sched_barrier(0);                                        \
  } while (0)

__global__ __launch_bounds__(512) void gemm_kernel(GP p) {
  // A regions: [(d*2+kh)*8192]; B regions: 32768 + [(d*2+kh)*8192]  (bf16 idx)
  __shared__ __align__(16) bf16_t Ls[65536];  // 128 KiB
  const int tid = threadIdx.x;
  const int wave = tid >> 6, lane = tid & 63;
  const int wr = wave >> 2, wc = wave & 3;  // 2 x 4 wave grid
  const int lrow = lane & 15, kq = lane >> 4;
  const int swz = (kq ^ ((lrow >> 1) & 3)) * 8;  // read slot (elements)
  // staging: lane covers row (lane>>2) of a 16-row group, LDS slot lane&3;
  // global source column slot = (lane&3) ^ ((lane>>3)&3)  (inverse swizzle)
  const int srow = lane >> 2;
  const int scol = ((lane & 3) ^ ((lane >> 3) & 3)) * 8;
  const int m0 = blockIdx.x * 256;
  const int n0 = blockIdx.y * 256;
  const int zs = (int)blockIdx.z;
  const int kc = p.K / p.ksplit;
  const int kstart = zs * kc;
  const int NT = kc >> 6;  // K-tiles of 64 (always even here)

  const bf16_t* gA = p.A + (long)(m0 + wave * 16 + srow) * p.lda + scol + kstart;
  const bf16_t* gB = p.B + (long)(n0 + wave * 16 + srow) * p.ldb + scol + kstart;
  const long strA = (long)128 * p.lda;
  const long strB = (long)128 * p.ldb;

  auto stA = [&](int d, int kh, int t) {
    const bf16_t* s = gA + t * 64 + kh * 32;
    bf16_t* l0 = &Ls[(d * 2 + kh) * 8192 + wave * 512];
    async_load16(s, l0);
    async_load16(s + strA, l0 + 4096);
  };
  auto stB = [&](int d, int kh, int t) {
    const bf16_t* s = gB + t * 64 + kh * 32;
    bf16_t* l0 = &Ls[32768 + (d * 2 + kh) * 8192 + wave * 512];
    async_load16(s, l0);
    async_load16(s + strB, l0 + 4096);
  };
  auto ldA = [&](int d, int kk, int mi) {
    return *(const bf16x8*)&Ls[(d * 2 + kk) * 8192 +
                               (wr * 128 + mi * 16 + lrow) * 32 + swz];
  };
  auto ldB = [&](int d, int kk, int j) {
    return *(const bf16x8*)&Ls[32768 + (d * 2 + kk) * 8192 +
                               (wc * 64 + j * 16 + lrow) * 32 + swz];
  };

  f32x4 acc[8][4] = {};
  bf16x8 bfr[4];

  // prologue: tile0 fully (8 loads), tile1 minus A.kh1 (6 loads).
  stA(0, 0, 0);
  stB(0, 0, 0);
  stA(0, 1, 0);
  stB(0, 1, 0);
  stB(1, 0, 1);
  stA(1, 0, 1);
  stB(1, 1, 1);
  VMCNT(6);  // tile0's 8 loads landed; tile1's 6 in flight
  __builtin_amdgcn_s_barrier();
  __builtin_amdgcn_sched_barrier(0);

  const int NI = NT >> 1;
  for (int it = 0; it < NI; ++it) {
    const int T = it * 2;
    const int t1 = T + 1;
    const int t2 = (T + 2 < NT) ? T + 2 : 0;  // wrap tail (data unused)
    const int t3 = (T + 3 < NT) ? T + 3 : 0;
    // K-tile T (buf0):
    PHASE(0, 0, 0, 1, stA(1, 1, t1));  // P1: buf1.A.kh1  (read P7/P8)
    PHASE(0, 0, 4, 0, stB(0, 0, t2));  // P2: buf0.B.kh0  (read next P1)
    PHASE(0, 1, 0, 1, stA(0, 0, t2));  // P3: buf0.A.kh0  (read next P1/P2)
    PHASE(0, 1, 4, 0, stB(0, 1, t2));  // P4: buf0.B.kh1  (read next P3)
    // K-tile T+1 (buf1):
    PHASE(1, 0, 0, 1, stA(0, 1, t2));  // P5: buf0.A.kh1  (read next P3/P4)
    PHASE(1, 0, 4, 0, stB(1, 0, t3));  // P6: buf1.B.kh0  (read next P5)
    PHASE(1, 1, 0, 1, stA(1, 0, t3));  // P7: buf1.A.kh0  (read next P5/P6)
    PHASE(1, 1, 4, 0, stB(1, 1, t3));  // P8: buf1.B.kh1  (read next P7)
  }
  VMCNT(0);  // drain wrapped tail stages before retire

  const int crow0 = m0 + wr * 128 + kq * 4;
  const int ccol0 = n0 + wc * 64 + lrow;
  if (p.ksplit > 1) {
    float* po = p.outF + (long)zs * p.pstride;
#pragma unroll
    for (int j = 0; j < 4; ++j) {
      const int col = ccol0 + j * 16;
#pragma unroll
      for (int i = 0; i < 8; ++i)
#pragma unroll
        for (int r = 0; r < 4; ++r)
          po[(long)(crow0 + i * 16 + r) * p.ldc + col] = acc[i][j][r];
    }
  } else {
#pragma unroll
    for (int j = 0; j < 4; ++j) {
      const int col = ccol0 + j * 16;
#pragma unroll
      for (int i = 0; i < 8; ++i) {
#pragma unroll
        for (int r = 0; r < 4; ++r) {
          const int row = crow0 + i * 16 + r;
          const long idx = (long)row * p.ldc + col;
          float y = acc[i][j][r];
          if (p.bias) y += p.bias[col];
          if (p.resid) y += p.resid[idx];
          if (p.act) y = gelu_f(y);
          if (p.outF) p.outF[idx] = y;
          if (p.outB) p.outB[idx] = (bf16_t)y;
        }
      }
    }
  }
}

// ---------- fused flash attention ----------
#define QT 64
#define KT 128
#define VPAD 136

__global__ __launch_bounds__(256) void attn_kernel(const bf16_t* __restrict__ qkv,
                                                   const int* __restrict__ toks,
                                                   bf16_t* __restrict__ ctx, int causal) {
  __shared__ __align__(16) bf16_t Qs[QT * 64];
  __shared__ __align__(16) bf16_t Ks[KT * 64];
  __shared__ __align__(16) bf16_t Vs[64 * VPAD];
  __shared__ __align__(16) bf16_t Ps[QT * VPAD];
  __shared__ int Ts[SEQ];
  const int tid = threadIdx.x;
  const int wave = tid >> 6, lane = tid & 63;
  const int lm = lane & 15, lq = lane >> 4;
  const int q0 = blockIdx.x * QT;
  const int bh = blockIdx.y;
  const int b = bh / NHEAD, h = bh % NHEAD;
  const long rowbase = (long)b * SEQ;
  const int LD = 3 * DMODEL;
  const bf16_t* Qg = qkv + (rowbase + q0) * LD + h * DHEAD;
  const bf16_t* Kg = qkv + rowbase * LD + DMODEL + h * DHEAD;
  const bf16_t* Vg = qkv + rowbase * LD + 2 * DMODEL + h * DHEAD;

  Ts[tid] = toks[b * SEQ + tid];
  Ts[tid + 256] = toks[b * SEQ + tid + 256];

#pragma unroll
  for (int r = 0; r < 2; ++r) {
    const int c = r * 256 + tid;
    const int row = c >> 3, c8 = (c & 7) * 8;
    async_load16(Qg + (long)row * LD + c8, &Qs[c * 8]);
  }
  __syncthreads();

  bf16x8 aQ0 = *(const bf16x8*)&Qs[(wave * 16 + lm) * 64 + lq * 8];
  bf16x8 aQ1 = *(const bf16x8*)&Qs[(wave * 16 + lm) * 64 + 32 + lq * 8];

  float m_i[4], l_i[4];
  f32x4 O[4] = {};
#pragma unroll
  for (int r = 0; r < 4; ++r) { m_i[r] = -3.0e38f; l_i[r] = 0.0f; }

  const int s_end = causal ? (q0 + QT) : SEQ;
  for (int s0 = 0; s0 < s_end; s0 += KT) {
    __syncthreads();
#pragma unroll
    for (int r = 0; r < 4; ++r) {
      const int c = r * 256 + tid;
      const int row = c >> 3, c8 = (c & 7) * 8;
      async_load16(Kg + (long)(s0 + row) * LD + c8, &Ks[c * 8]);
    }
#pragma unroll
    for (int r = 0; r < 4; ++r) {
      const int c = r * 256 + tid;
      const int row = c >> 3, c8 = (c & 7) * 8;
      const bf16x8 vv = *(const bf16x8*)(Vg + (long)(s0 + row) * LD + c8);
#pragma unroll
      for (int j = 0; j < 8; ++j) Vs[(c8 + j) * VPAD + row] = vv[j];
    }
    __syncthreads();

    f32x4 sv[8];
#pragma unroll
    for (int jt = 0; jt < 8; ++jt) {
      const bf16x8 b0 = *(const bf16x8*)&Ks[(jt * 16 + lm) * 64 + lq * 8];
      const bf16x8 b1 = *(const bf16x8*)&Ks[(jt * 16 + lm) * 64 + 32 + lq * 8];
      f32x4 a = {};
      a = __builtin_amdgcn_mfma_f32_16x16x32_bf16(aQ0, b0, a, 0, 0, 0);
      a = __builtin_amdgcn_mfma_f32_16x16x32_bf16(aQ1, b1, a, 0, 0, 0);
      sv[jt] = a;
    }

#pragma unroll
    for (int r = 0; r < 4; ++r) {
      const int qa = q0 + wave * 16 + lq * 4 + r;
      float sr[8];
      float mx = -3.0e38f;
#pragma unroll
      for (int jt = 0; jt < 8; ++jt) {
        const int k = s0 + jt * 16 + lm;
        const float x = sv[jt][r] * 0.125f;
        const bool msk = (Ts[k] == 0) || (causal && (k > qa));
        sr[jt] = msk ? -1.0e18f : x;
        mx = fmaxf(mx, sr[jt]);
      }
#pragma unroll
      for (int o = 1; o < 16; o <<= 1) mx = fmaxf(mx, __shfl_xor(mx, o, 64));
      const float mn = fmaxf(m_i[r], mx);
      const float alpha = __expf(m_i[r] - mn);
      float sum = 0.0f;
#pragma unroll
      for (int jt = 0; jt < 8; ++jt) {
        const float pv = __expf(sr[jt] - mn);
        sr[jt] = pv;
        sum += pv;
      }
#pragma unroll
      for (int o = 1; o < 16; o <<= 1) sum += __shfl_xor(sum, o, 64);
      l_i[r] = l_i[r] * alpha + sum;
      m_i[r] = mn;
#pragma unroll
      for (int jn = 0; jn < 4; ++jn) O[jn][r] *= alpha;
#pragma unroll
      for (int jt = 0; jt < 8; ++jt)
        Ps[(wave * 16 + lq * 4 + r) * VPAD + jt * 16 + lm] = (bf16_t)sr[jt];
    }

#pragma unroll
    for (int kt = 0; kt < 4; ++kt) {
      const bf16x8 aP = *(const bf16x8*)&Ps[(wave * 16 + lm) * VPAD + kt * 32 + lq * 8];
#pragma unroll
      for (int jn = 0; jn < 4; ++jn) {
        const bf16x8 bV = *(const bf16x8*)&Vs[(jn * 16 + lm) * VPAD + kt * 32 + lq * 8];
        O[jn] = __builtin_amdgcn_mfma_f32_16x16x32_bf16(aP, bV, O[jn], 0, 0, 0);
      }
    }
  }

#pragma unroll
  for (int r = 0; r < 4; ++r) {
    const int q = q0 + wave * 16 + lq * 4 + r;
    const float inv = 1.0f / l_i[r];
#pragma unroll
    for (int jn = 0; jn < 4; ++jn) {
      const int d = jn * 16 + lm;
      ctx[(rowbase + q) * DMODEL + h * DHEAD + d] = (bf16_t)(O[jn][r] * inv);
    }
  }
}

// ---------- LayerNorm (row = 768) ----------
__global__ __launch_bounds__(256) void ln_kernel(const float* __restrict__ X,
                                                 const float* __restrict__ g,
                                                 const float* __restrict__ b,
                                                 bf16_t* __restrict__ outB,
                                                 float* __restrict__ outF) {
  const int row = blockIdx.x, tid = threadIdx.x;
  const float* xr = X + (long)row * DMODEL;
  const float v0 = xr[tid], v1 = xr[tid + 256], v2 = xr[tid + 512];
  __shared__ float r1[4], r2[4];
  const int wv = tid >> 6, ln = tid & 63;
  float s = wsum(v0 + v1 + v2);
  if (ln == 0) r1[wv] = s;
  __syncthreads();
  const float mean = (r1[0] + r1[1] + r1[2] + r1[3]) * (1.0f / DMODEL);
  const float d0 = v0 - mean, d1 = v1 - mean, d2 = v2 - mean;
  float q = wsum(d0 * d0 + d1 * d1 + d2 * d2);
  if (ln == 0) r2[wv] = q;
  __syncthreads();
  const float var = (r2[0] + r2[1] + r2[2] + r2[3]) * (1.0f / DMODEL);
  const float rs = rsqrtf(var + 1e-6f);
  const float y0 = d0 * rs * g[tid] + b[tid];
  const float y1 = d1 * rs * g[tid + 256] + b[tid + 256];
  const float y2 = d2 * rs * g[tid + 512] + b[tid + 512];
  const long base = (long)row * DMODEL;
  if (outB) {
    outB[base + tid] = (bf16_t)y0;
    outB[base + tid + 256] = (bf16_t)y1;
    outB[base + tid + 512] = (bf16_t)y2;
  }
  if (outF) {
    outF[base + tid] = y0;
    outF[base + tid + 256] = y1;
    outF[base + tid + 512] = y2;
  }
}

// ---------- reduce split-K partials + bias + residual, then LayerNorm ----------
__global__ __launch_bounds__(256) void reduce_ln_kernel(
    const float* __restrict__ parts, long pstr, int np,
    const float* __restrict__ bias, float* __restrict__ res,
    const float* __restrict__ g, const float* __restrict__ b,
    bf16_t* __restrict__ outB, float* __restrict__ outF) {
  const int row = blockIdx.x, tid = threadIdx.x;
  const long base = (long)row * DMODEL;
  float v0, v1, v2;
  {
    float t0 = res[base + tid] + bias[tid];
    float t1 = res[base + tid + 256] + bias[tid + 256];
    float t2 = res[base + tid + 512] + bias[tid + 512];
    for (int p = 0; p < np; ++p) {
      const float* pp = parts + p * pstr + base;
      t0 += pp[tid];
      t1 += pp[tid + 256];
      t2 += pp[tid + 512];
    }
    v0 = t0; v1 = t1; v2 = t2;
    res[base + tid] = t0;
    res[base + tid + 256] = t1;
    res[base + tid + 512] = t2;
  }
  __shared__ float r1[4], r2[4];
  const int wv = tid >> 6, ln = tid & 63;
  float s = wsum(v0 + v1 + v2);
  if (ln == 0) r1[wv] = s;
  __syncthreads();
  const float mean = (r1[0] + r1[1] + r1[2] + r1[3]) * (1.0f / DMODEL);
  const float d0 = v0 - mean, d1 = v1 - mean, d2 = v2 - mean;
  float q = wsum(d0 * d0 + d1 * d1 + d2 * d2);
  if (ln == 0) r2[wv] = q;
  __syncthreads();
  const float var = (r2[0] + r2[1] + r2[2] + r2[3]) * (1.0f / DMODEL);
  const float rs = rsqrtf(var + 1e-6f);
  const float y0 = d0 * rs * g[tid] + b[tid];
  const float y1 = d1 * rs * g[tid + 256] + b[tid + 256];
  const float y2 = d2 * rs * g[tid + 512] + b[tid + 512];
  if (outB) {
    outB[base + tid] = (bf16_t)y0;
    outB[base + tid + 256] = (bf16_t)y1;
    outB[base + tid + 512] = (bf16_t)y2;
  }
  if (outF) {
    outF[base + tid] = y0;
    outF[base + tid + 256] = y1;
    outF[base + tid + 512] = y2;
  }
}

// ---------- reduce split-K partials + bias -> strided bf16 (CA-q into qkv) ----------
__global__ __launch_bounds__(256) void reduce_cvtq_kernel(
    const float* __restrict__ parts, long pstr, int np,
    const float* __restrict__ bias, bf16_t* __restrict__ o) {
  const int row = blockIdx.x, tid = threadIdx.x;
  const long base = (long)row * DMODEL;
  const long ob = (long)row * 3 * DMODEL;
#pragma unroll
  for (int c = 0; c < 3; ++c) {
    const int col = tid + c * 256;
    float t = bias[col];
    for (int p = 0; p < np; ++p) t += parts[p * pstr + base + col];
    o[ob + col] = (bf16_t)t;
  }
}

// ---------- embedding * sqrt(D) + sinusoidal PE ----------
__global__ __launch_bounds__(256) void emb_kernel(const int* __restrict__ tgt,
                                                  const float* __restrict__ tab,
                                                  float* __restrict__ res) {
  const int row = blockIdx.x;
  const int t = row & (SEQ - 1);
  const long tok = tgt[row];
  const float* er = tab + tok * DMODEL;
  float* orow = res + (long)row * DMODEL;
  const float c1 = -9.210340371976184f / 768.0f;
  for (int c = threadIdx.x; c < DMODEL; c += 256) {
    const float e = er[c] * 27.712812921102035f;
    const float div = expf((float)(c & ~1) * c1);
    const float ang = (float)t * div;
    const float pe = (c & 1) ? cosf(ang) : sinf(ang);
    orow[c] = e + pe;
  }
}

// ---------- f32 -> bf16 convert (n4 = n/4) ----------
__global__ __launch_bounds__(256) void cvt_kernel(const float* __restrict__ in,
                                                  bf16_t* __restrict__ o, int n4) {
  const int i = blockIdx.x * 256 + threadIdx.x;
  if (i < n4) {
    const float4 v = ((const float4*)in)[i];
    bf16x4 r = {(bf16_t)v.x, (bf16_t)v.y, (bf16_t)v.z, (bf16_t)v.w};
    ((bf16x4*)o)[i] = r;
  }
}

// ---------- host ----------
extern "C" void kernel_launch(void* const* d_in, const int* in_sizes, int n_in,
                              void* d_out, int out_size, void* d_ws, size_t ws_size,
                              hipStream_t stream) {
  (void)in_sizes; (void)n_in; (void)out_size; (void)ws_size;
  const int* tgt = (const int*)d_in[0];
  const int* srct = (const int*)d_in[1];
  const float* memb = (const float*)d_in[2];
  const float* embt = (const float*)d_in[3];
  const float* sa_w = (const float*)d_in[4];
  const float* sa_b = (const float*)d_in[5];
  const float* ca_w = (const float*)d_in[6];
  const float* ca_b = (const float*)d_in[7];
  const float* ln_g = (const float*)d_in[8];
  const float* ln_b = (const float*)d_in[9];
  const float* ff_w1 = (const float*)d_in[10];
  const float* ff_b1 = (const float*)d_in[11];
  const float* ff_w2 = (const float*)d_in[12];
  const float* ff_b2 = (const float*)d_in[13];
  const float* out_g = (const float*)d_in[14];
  const float* out_b = (const float*)d_in[15];
  float* out = (float*)d_out;

  char* wsb = (char*)d_ws;
  size_t off = 0;
  auto alloc = [&](size_t bytes) -> void* {
    void* pp = wsb + off;
    off = (off + bytes + 255) & ~(size_t)255;
    return pp;
  };
  // NOTE: allocation ORDER and SIZES are load-bearing: FFN2 uses ksplit=4 and
  // its partials span parts(2*PSTR) + xb + qkvb exactly (both dead at that point).
  float* res = (float*)alloc((size_t)MROWS * DMODEL * 4);
  float* parts = (float*)alloc((size_t)2 * MROWS * DMODEL * 4);  // split-K partials 0..1
  bf16_t* xb = (bf16_t*)alloc((size_t)MROWS * DMODEL * 2);       // = parts[2] during FFN2
  bf16_t* qkvb = (bf16_t*)alloc((size_t)MROWS * 3 * DMODEL * 2); // = parts[3] during FFN2
  bf16_t* ctxb = (bf16_t*)alloc((size_t)MROWS * DMODEL * 2);
  bf16_t* membb = (bf16_t*)alloc((size_t)MROWS * DMODEL * 2);
  bf16_t* ffh = (bf16_t*)alloc((size_t)MROWS * DFFN * 2);
  bf16_t* wA = (bf16_t*)alloc((size_t)4 * DMODEL * DMODEL * 2);
  bf16_t* wF1 = (bf16_t*)alloc((size_t)DFFN * DMODEL * 2);
  bf16_t* wF2 = (bf16_t*)alloc((size_t)DFFN * DMODEL * 2);

  const long PSTR = (long)MROWS * DMODEL;

  auto gemm = [&](const bf16_t* A, const bf16_t* Bm, const float* bias,
                  const float* resid, float* oF, bf16_t* oB, int M, int N, int K,
                  int lda, int ldb, int ldc, int act, int ksplit) {
    GP p{A, Bm, bias, resid, oF, oB, M, N, K, lda, ldb, ldc, PSTR, act, ksplit};
    dim3 g((unsigned)(M / 256), (unsigned)(N / 256), (unsigned)ksplit);
    gemm_kernel<<<g, 512, 0, stream>>>(p);
  };

  const long WSZ = (long)DMODEL * DMODEL;

  emb_kernel<<<MROWS, 256, 0, stream>>>(tgt, embt, res);
  cvt_kernel<<<(MROWS * DMODEL / 4 + 255) / 256, 256, 0, stream>>>(memb, membb,
                                                                   MROWS * DMODEL / 4);
  // ln1 output lives in ctxb (QKV input); xb stays dead across FFN2's aliased partials
  ln_kernel<<<MROWS, 256, 0, stream>>>(res, ln_g, ln_b, ctxb, nullptr);

  for (int l = 0; l < NLAYER; ++l) {
    const float* saw = sa_w + (long)l * 4 * WSZ;
    const float* sab = sa_b + (long)l * 4 * DMODEL;
    const float* caw = ca_w + (long)l * 4 * WSZ;
    const float* cab = ca_b + (long)l * 4 * DMODEL;

    // ======== self-attention ========   (ctxb = ln1(res))
    cvt_kernel<<<(int)((WSZ + 255) / 256), 256, 0, stream>>>(saw, wA, (int)WSZ);
    gemm(ctxb, wA, sab, nullptr, nullptr, qkvb, MROWS, 3 * DMODEL, DMODEL,
         DMODEL, DMODEL, 3 * DMODEL, 0, 1);
    attn_kernel<<<dim3(SEQ / QT, BATCH * NHEAD), 256, 0, stream>>>(qkvb, tgt, ctxb, 1);
    gemm(ctxb, wA + 3 * WSZ, nullptr, nullptr, parts, nullptr, MROWS, DMODEL, DMODEL,
         DMODEL, DMODEL, DMODEL, 0, 2);
    reduce_ln_kernel<<<MROWS, 256, 0, stream>>>(parts, PSTR, 2, sab + 3 * DMODEL, res,
                                                ln_g + (l * 3 + 1) * DMODEL,
                                                ln_b + (l * 3 + 1) * DMODEL, xb, nullptr);

    // ======== cross-attention ========  (xb = ln2)
    cvt_kernel<<<(int)((WSZ + 255) / 256), 256, 0, stream>>>(caw, wA, (int)WSZ);
    gemm(xb, wA, nullptr, nullptr, parts, nullptr, MROWS, DMODEL, DMODEL,
         DMODEL, DMODEL, DMODEL, 0, 2);
    reduce_cvtq_kernel<<<MROWS, 256, 0, stream>>>(parts, PSTR, 2, cab, qkvb);
    gemm(membb, wA + WSZ, cab + DMODEL, nullptr, nullptr, qkvb + DMODEL, MROWS,
         2 * DMODEL, DMODEL, DMODEL, DMODEL, 3 * DMODEL, 0, 1);
    attn_kernel<<<dim3(SEQ / QT, BATCH * NHEAD), 256, 0, stream>>>(qkvb, srct, ctxb, 0);
    gemm(ctxb, wA + 3 * WSZ, nullptr, nullptr, parts, nullptr, MROWS, DMODEL, DMODEL,
         DMODEL, DMODEL, DMODEL, 0, 2);
    reduce_ln_kernel<<<MROWS, 256, 0, stream>>>(parts, PSTR, 2, cab + 3 * DMODEL, res,
                                                ln_g + (l * 3 + 2) * DMODEL,
                                                ln_b + (l * 3 + 2) * DMODEL, xb, nullptr);

    // ======== FFN ========  (xb = ln3)
    cvt_kernel<<<(int)((DFFN * (long)DMODEL / 4 + 255) / 256), 256, 0, stream>>>(
        ff_w1 + (long)l * DFFN * DMODEL, wF1, (int)(DFFN * (long)DMODEL / 4));
    cvt_kernel<<<(int)((DFFN * (long)DMODEL / 4 + 255) / 256), 256, 0, stream>>>(
        ff_w2 + (long)l * DFFN * DMODEL, wF2, (int)(DFFN * (long)DMODEL / 4));
    gemm(xb, wF1, ff_b1 + (long)l * DFFN, nullptr, nullptr, ffh, MROWS, DFFN,
         DMODEL, DMODEL, DMODEL, DFFN, 1, 1);
    // ksplit=4: partials 2,3 alias xb/qkvb (dead here); reduce writes ln1 -> ctxb
    gemm(ffh, wF2, nullptr, nullptr, parts, nullptr, MROWS, DMODEL, DFFN,
         DFFN, DFFN, DMODEL, 0, 4);
    if (l < NLAYER - 1) {
      reduce_ln_kernel<<<MROWS, 256, 0, stream>>>(parts, PSTR, 4, ff_b2 + (long)l * DMODEL,
                                                  res, ln_g + ((l + 1) * 3) * DMODEL,
                                                  ln_b + ((l + 1) * 3) * DMODEL, ctxb, nullptr);
    } else {
      reduce_ln_kernel<<<MROWS, 256, 0, stream>>>(parts, PSTR, 4, ff_b2 + (long)l * DMODEL,
                                                  res, out_g, out_b, nullptr, out);
    }
  }
}

// Round 3
// 2498.275 us; speedup vs baseline: 1.0865x; 1.0865x over previous
//
#include <hip/hip_runtime.h>
#include <math.h>
#include <stdint.h>

typedef __bf16 bf16_t;
typedef __bf16 bf16x8 __attribute__((ext_vector_type(8)));
typedef __bf16 bf16x4 __attribute__((ext_vector_type(4)));
typedef float f32x4 __attribute__((ext_vector_type(4)));

#define NLAYER 6
#define DMODEL 768
#define NHEAD 12
#define DHEAD 64
#define SEQ 512
#define BATCH 8
#define MROWS 4096 /* BATCH*SEQ */
#define DFFN 3072

// ---------- helpers ----------

__device__ inline void async_load16(const void* g, void* lds) {
  const __attribute__((address_space(1))) void* gp =
      (const __attribute__((address_space(1))) void*)(uintptr_t)g;
  __attribute__((address_space(3))) void* lp =
      (__attribute__((address_space(3))) void*)(uint32_t)(uintptr_t)lds;
  __builtin_amdgcn_global_load_lds(gp, lp, 16, 0, 0);
}

#define VMCNT(n) __builtin_amdgcn_s_waitcnt(0x0F70 | (n))
#define WAIT_ALL __builtin_amdgcn_s_waitcnt(0x0070) /* vmcnt(0) lgkmcnt(0) */

__device__ inline float wsum(float v) {
#pragma unroll
  for (int o = 32; o > 0; o >>= 1) v += __shfl_xor(v, o, 64);
  return v;
}

__device__ inline float gelu_f(float x) {
  float u = 0.7978845608028654f * (x + 0.044715f * x * x * x);
  return 0.5f * x * (1.0f + tanhf(u));
}

struct GP {
  const bf16_t* A;
  const bf16_t* B;
  const float* bias;   // [N] or null (ignored when ksplit>1)
  const float* resid;  // f32, ldc layout, or null
  float* outF;         // f32 out (or partial base when ksplit>1)
  bf16_t* outB;        // bf16 out or null
  int M, N, K;
  int lda, ldb, ldc;
  long pstride;  // partial-buffer stride (elements) for ksplit>1
  int act;       // 1 = gelu
  int ksplit;
};

// ---------- 128x128 GEMM (round-0 proven kernel) ----------
__global__ __launch_bounds__(256) void gemm128(GP p) {
  __shared__ __align__(16) bf16_t As[2][128 * 32];
  __shared__ __align__(16) bf16_t Bs[2][128 * 32];
  const int tid = threadIdx.x;
  const int wave = tid >> 6, lane = tid & 63;
  const int wr = wave >> 1, wc = wave & 1;
  const int lrow = lane & 15, kq = lane >> 4;
  const int sr = tid >> 2;
  const int sc = (tid & 3) << 3;
  const int m0 = blockIdx.x * 128;
  const int n0 = blockIdx.y * 128;
  const int zs = (int)blockIdx.z;

  const int kc = p.K / p.ksplit;
  const int kstart = zs * kc;
  const int kend = kstart + kc;

  auto stage = [&](int k0, int buf) {
#pragma unroll
    for (int r = 0; r < 2; ++r)
      async_load16(p.A + (long)(m0 + r * 64 + sr) * p.lda + (k0 + sc),
                   &As[buf][(r * 64 + wave * 16) * 32]);
#pragma unroll
    for (int r = 0; r < 2; ++r)
      async_load16(p.B + (long)(n0 + r * 64 + sr) * p.ldb + (k0 + sc),
                   &Bs[buf][(r * 64 + wave * 16) * 32]);
  };

  f32x4 acc[4][4] = {};
  stage(kstart, 0);
  int cur = 0;

  for (int k0 = kstart; k0 < kend; k0 += 32) {
    const bool hn = (k0 + 32) < kend;
    if (hn) {
      stage(k0 + 32, cur ^ 1);
      __builtin_amdgcn_s_waitcnt(0xF74);  // vmcnt(4): cur buf's 4 loads done
    } else {
      __builtin_amdgcn_s_waitcnt(0xF70);  // vmcnt(0)
    }
    __builtin_amdgcn_s_barrier();

    bf16x8 af[4], bfr[4];
#pragma unroll
    for (int i = 0; i < 4; ++i)
      af[i] = *(const bf16x8*)&As[cur][(wr * 64 + i * 16 + lrow) * 32 + kq * 8];
#pragma unroll
    for (int j = 0; j < 4; ++j)
      bfr[j] = *(const bf16x8*)&Bs[cur][(wc * 64 + j * 16 + lrow) * 32 + kq * 8];
#pragma unroll
    for (int i = 0; i < 4; ++i)
#pragma unroll
      for (int j = 0; j < 4; ++j)
        acc[i][j] = __builtin_amdgcn_mfma_f32_16x16x32_bf16(af[i], bfr[j], acc[i][j], 0, 0, 0);

    __builtin_amdgcn_s_barrier();  // all waves done reading cur before overwrite
    cur ^= 1;
  }

  const int crow0 = m0 + wr * 64 + kq * 4;
  const int ccol0 = n0 + wc * 64 + lrow;
  if (p.ksplit > 1) {
    float* po = p.outF + (long)zs * p.pstride;
#pragma unroll
    for (int j = 0; j < 4; ++j) {
      const int col = ccol0 + j * 16;
#pragma unroll
      for (int i = 0; i < 4; ++i)
#pragma unroll
        for (int r = 0; r < 4; ++r)
          po[(long)(crow0 + i * 16 + r) * p.ldc + col] = acc[i][j][r];
    }
  } else {
#pragma unroll
    for (int j = 0; j < 4; ++j) {
      const int col = ccol0 + j * 16;
#pragma unroll
      for (int i = 0; i < 4; ++i) {
#pragma unroll
        for (int r = 0; r < 4; ++r) {
          const int row = crow0 + i * 16 + r;
          const long idx = (long)row * p.ldc + col;
          float y = acc[i][j][r];
          if (p.bias) y += p.bias[col];
          if (p.resid) y += p.resid[idx];
          if (p.act) y = gelu_f(y);
          if (p.outF) p.outF[idx] = y;
          if (p.outB) p.outB[idx] = (bf16_t)y;
        }
      }
    }
  }
}

// ---------- 256x256 GEMM, A/B experiment ----------
// V=0: round-2 8-phase schedule (control arm, unchanged).
// V=1: stripped minimum-2-phase loop (m248 pattern): stage-next, ds_read,
//      MFMA, one vmcnt(0)+lgkmcnt(0)+__syncthreads per K-tile. No setprio,
//      no sched_barrier, no raw barriers. Same LDS layout/swizzle as V0.

#define PHASE(d, kk, mb, LOADB, STAGE)                                        \
  do {                                                                        \
    bf16x8 a_[4];                                                             \
    _Pragma("unroll") for (int i_ = 0; i_ < 4; ++i_) a_[i_] =                 \
        ldA(d, kk, (mb) + i_);                                                \
    if (LOADB) {                                                              \
      _Pragma("unroll") for (int j_ = 0; j_ < 4; ++j_) bfr[j_] =              \
          ldB(d, kk, j_);                                                     \
    }                                                                         \
    STAGE;                                                                    \
    __builtin_amdgcn_s_barrier();                                             \
    __builtin_amdgcn_s_setprio(1);                                            \
    _Pragma("unroll") for (int i_ = 0; i_ < 4; ++i_)                          \
        _Pragma("unroll") for (int j_ = 0; j_ < 4; ++j_) acc[(mb) + i_][j_] = \
            __builtin_amdgcn_mfma_f32_16x16x32_bf16(a_[i_], bfr[j_],          \
                                                    acc[(mb) + i_][j_], 0, 0, \
                                                    0);                       \
    __builtin_amdgcn_s_setprio(0);                                            \
    VMCNT(10);                                                                \
    __builtin_amdgcn_sched_barrier(0);                                        \
    __builtin_amdgcn_s_barrier();                                             \
    __builtin_amdgcn_sched_barrier(0);                                        \
  } while (0)

template <int V>
__global__ __launch_bounds__(512) void gemm256(GP p) {
  // A regions: [(d*2+kh)*8192]; B regions: 32768 + [(d*2+kh)*8192]  (bf16 idx)
  __shared__ __align__(16) bf16_t Ls[65536];  // 128 KiB
  const int tid = threadIdx.x;
  const int wave = tid >> 6, lane = tid & 63;
  const int wr = wave >> 2, wc = wave & 3;  // 2 x 4 wave grid
  const int lrow = lane & 15, kq = lane >> 4;
  const int swz = (kq ^ ((lrow >> 1) & 3)) * 8;  // read slot (elements)
  const int srow = lane >> 2;
  const int scol = ((lane & 3) ^ ((lane >> 3) & 3)) * 8;
  const int m0 = blockIdx.x * 256;
  const int n0 = blockIdx.y * 256;
  const int zs = (int)blockIdx.z;
  const int kc = p.K / p.ksplit;
  const int kstart = zs * kc;
  const int NT = kc >> 6;  // K-tiles of 64 (always even here)

  const bf16_t* gA = p.A + (long)(m0 + wave * 16 + srow) * p.lda + scol + kstart;
  const bf16_t* gB = p.B + (long)(n0 + wave * 16 + srow) * p.ldb + scol + kstart;
  const long strA = (long)128 * p.lda;
  const long strB = (long)128 * p.ldb;

  auto stA = [&](int d, int kh, int t) {
    const bf16_t* s = gA + t * 64 + kh * 32;
    bf16_t* l0 = &Ls[(d * 2 + kh) * 8192 + wave * 512];
    async_load16(s, l0);
    async_load16(s + strA, l0 + 4096);
  };
  auto stB = [&](int d, int kh, int t) {
    const bf16_t* s = gB + t * 64 + kh * 32;
    bf16_t* l0 = &Ls[32768 + (d * 2 + kh) * 8192 + wave * 512];
    async_load16(s, l0);
    async_load16(s + strB, l0 + 4096);
  };
  auto ldA = [&](int d, int kk, int mi) {
    return *(const bf16x8*)&Ls[(d * 2 + kk) * 8192 +
                               (wr * 128 + mi * 16 + lrow) * 32 + swz];
  };
  auto ldB = [&](int d, int kk, int j) {
    return *(const bf16x8*)&Ls[32768 + (d * 2 + kk) * 8192 +
                               (wc * 64 + j * 16 + lrow) * 32 + swz];
  };

  f32x4 acc[8][4] = {};

  if constexpr (V == 0) {
    bf16x8 bfr[4];
    // prologue: tile0 fully (8 loads), tile1 minus A.kh1 (6 loads).
    stA(0, 0, 0);
    stB(0, 0, 0);
    stA(0, 1, 0);
    stB(0, 1, 0);
    stB(1, 0, 1);
    stA(1, 0, 1);
    stB(1, 1, 1);
    VMCNT(6);
    __builtin_amdgcn_s_barrier();
    __builtin_amdgcn_sched_barrier(0);

    const int NI = NT >> 1;
    for (int it = 0; it < NI; ++it) {
      const int T = it * 2;
      const int t1 = T + 1;
      const int t2 = (T + 2 < NT) ? T + 2 : 0;  // wrap tail (data unused)
      const int t3 = (T + 3 < NT) ? T + 3 : 0;
      PHASE(0, 0, 0, 1, stA(1, 1, t1));
      PHASE(0, 0, 4, 0, stB(0, 0, t2));
      PHASE(0, 1, 0, 1, stA(0, 0, t2));
      PHASE(0, 1, 4, 0, stB(0, 1, t2));
      PHASE(1, 0, 0, 1, stA(0, 1, t2));
      PHASE(1, 0, 4, 0, stB(1, 0, t3));
      PHASE(1, 1, 0, 1, stA(1, 0, t3));
      PHASE(1, 1, 4, 0, stB(1, 1, t3));
    }
    VMCNT(0);
  } else {
    // V1: minimum 2-phase, compiler-scheduled.
    stA(0, 0, 0);
    stA(0, 1, 0);
    stB(0, 0, 0);
    stB(0, 1, 0);
    WAIT_ALL;
    __syncthreads();
    int cur = 0;
    for (int t = 0; t < NT; ++t) {
      if (t + 1 < NT) {
        stA(cur ^ 1, 0, t + 1);
        stA(cur ^ 1, 1, t + 1);
        stB(cur ^ 1, 0, t + 1);
        stB(cur ^ 1, 1, t + 1);
      }
#pragma unroll
      for (int kk = 0; kk < 2; ++kk) {
        bf16x8 av[8], bv[4];
#pragma unroll
        for (int i = 0; i < 8; ++i) av[i] = ldA(cur, kk, i);
#pragma unroll
        for (int j = 0; j < 4; ++j) bv[j] = ldB(cur, kk, j);
#pragma unroll
        for (int i = 0; i < 8; ++i)
#pragma unroll
          for (int j = 0; j < 4; ++j)
            acc[i][j] =
                __builtin_amdgcn_mfma_f32_16x16x32_bf16(av[i], bv[j], acc[i][j], 0, 0, 0);
      }
      WAIT_ALL;      // reads of cur done + this iter's loads landed
      __syncthreads();
      cur ^= 1;
    }
  }

  const int crow0 = m0 + wr * 128 + kq * 4;
  const int ccol0 = n0 + wc * 64 + lrow;
  if (p.ksplit > 1) {
    float* po = p.outF + (long)zs * p.pstride;
#pragma unroll
    for (int j = 0; j < 4; ++j) {
      const int col = ccol0 + j * 16;
#pragma unroll
      for (int i = 0; i < 8; ++i)
#pragma unroll
        for (int r = 0; r < 4; ++r)
          po[(long)(crow0 + i * 16 + r) * p.ldc + col] = acc[i][j][r];
    }
  } else {
#pragma unroll
    for (int j = 0; j < 4; ++j) {
      const int col = ccol0 + j * 16;
#pragma unroll
      for (int i = 0; i < 8; ++i) {
#pragma unroll
        for (int r = 0; r < 4; ++r) {
          const int row = crow0 + i * 16 + r;
          const long idx = (long)row * p.ldc + col;
          float y = acc[i][j][r];
          if (p.bias) y += p.bias[col];
          if (p.resid) y += p.resid[idx];
          if (p.act) y = gelu_f(y);
          if (p.outF) p.outF[idx] = y;
          if (p.outB) p.outB[idx] = (bf16_t)y;
        }
      }
    }
  }
}

// ---------- fused flash attention ----------
#define QT 64
#define KT 128
#define VPAD 136

__global__ __launch_bounds__(256) void attn_kernel(const bf16_t* __restrict__ qkv,
                                                   const int* __restrict__ toks,
                                                   bf16_t* __restrict__ ctx, int causal) {
  __shared__ __align__(16) bf16_t Qs[QT * 64];
  __shared__ __align__(16) bf16_t Ks[KT * 64];
  __shared__ __align__(16) bf16_t Vs[64 * VPAD];
  __shared__ __align__(16) bf16_t Ps[QT * VPAD];
  __shared__ int Ts[SEQ];
  const int tid = threadIdx.x;
  const int wave = tid >> 6, lane = tid & 63;
  const int lm = lane & 15, lq = lane >> 4;
  const int q0 = blockIdx.x * QT;
  const int bh = blockIdx.y;
  const int b = bh / NHEAD, h = bh % NHEAD;
  const long rowbase = (long)b * SEQ;
  const int LD = 3 * DMODEL;
  const bf16_t* Qg = qkv + (rowbase + q0) * LD + h * DHEAD;
  const bf16_t* Kg = qkv + rowbase * LD + DMODEL + h * DHEAD;
  const bf16_t* Vg = qkv + rowbase * LD + 2 * DMODEL + h * DHEAD;

  Ts[tid] = toks[b * SEQ + tid];
  Ts[tid + 256] = toks[b * SEQ + tid + 256];

#pragma unroll
  for (int r = 0; r < 2; ++r) {
    const int c = r * 256 + tid;
    const int row = c >> 3, c8 = (c & 7) * 8;
    async_load16(Qg + (long)row * LD + c8, &Qs[c * 8]);
  }
  __syncthreads();

  bf16x8 aQ0 = *(const bf16x8*)&Qs[(wave * 16 + lm) * 64 + lq * 8];
  bf16x8 aQ1 = *(const bf16x8*)&Qs[(wave * 16 + lm) * 64 + 32 + lq * 8];

  float m_i[4], l_i[4];
  f32x4 O[4] = {};
#pragma unroll
  for (int r = 0; r < 4; ++r) { m_i[r] = -3.0e38f; l_i[r] = 0.0f; }

  const int s_end = causal ? (q0 + QT) : SEQ;
  for (int s0 = 0; s0 < s_end; s0 += KT) {
    __syncthreads();
#pragma unroll
    for (int r = 0; r < 4; ++r) {
      const int c = r * 256 + tid;
      const int row = c >> 3, c8 = (c & 7) * 8;
      async_load16(Kg + (long)(s0 + row) * LD + c8, &Ks[c * 8]);
    }
#pragma unroll
    for (int r = 0; r < 4; ++r) {
      const int c = r * 256 + tid;
      const int row = c >> 3, c8 = (c & 7) * 8;
      const bf16x8 vv = *(const bf16x8*)(Vg + (long)(s0 + row) * LD + c8);
#pragma unroll
      for (int j = 0; j < 8; ++j) Vs[(c8 + j) * VPAD + row] = vv[j];
    }
    __syncthreads();

    f32x4 sv[8];
#pragma unroll
    for (int jt = 0; jt < 8; ++jt) {
      const bf16x8 b0 = *(const bf16x8*)&Ks[(jt * 16 + lm) * 64 + lq * 8];
      const bf16x8 b1 = *(const bf16x8*)&Ks[(jt * 16 + lm) * 64 + 32 + lq * 8];
      f32x4 a = {};
      a = __builtin_amdgcn_mfma_f32_16x16x32_bf16(aQ0, b0, a, 0, 0, 0);
      a = __builtin_amdgcn_mfma_f32_16x16x32_bf16(aQ1, b1, a, 0, 0, 0);
      sv[jt] = a;
    }

#pragma unroll
    for (int r = 0; r < 4; ++r) {
      const int qa = q0 + wave * 16 + lq * 4 + r;
      float sr[8];
      float mx = -3.0e38f;
#pragma unroll
      for (int jt = 0; jt < 8; ++jt) {
        const int k = s0 + jt * 16 + lm;
        const float x = sv[jt][r] * 0.125f;
        const bool msk = (Ts[k] == 0) || (causal && (k > qa));
        sr[jt] = msk ? -1.0e18f : x;
        mx = fmaxf(mx, sr[jt]);
      }
#pragma unroll
      for (int o = 1; o < 16; o <<= 1) mx = fmaxf(mx, __shfl_xor(mx, o, 64));
      const float mn = fmaxf(m_i[r], mx);
      const float alpha = __expf(m_i[r] - mn);
      float sum = 0.0f;
#pragma unroll
      for (int jt = 0; jt < 8; ++jt) {
        const float pv = __expf(sr[jt] - mn);
        sr[jt] = pv;
        sum += pv;
      }
#pragma unroll
      for (int o = 1; o < 16; o <<= 1) sum += __shfl_xor(sum, o, 64);
      l_i[r] = l_i[r] * alpha + sum;
      m_i[r] = mn;
#pragma unroll
      for (int jn = 0; jn < 4; ++jn) O[jn][r] *= alpha;
#pragma unroll
      for (int jt = 0; jt < 8; ++jt)
        Ps[(wave * 16 + lq * 4 + r) * VPAD + jt * 16 + lm] = (bf16_t)sr[jt];
    }

#pragma unroll
    for (int kt = 0; kt < 4; ++kt) {
      const bf16x8 aP = *(const bf16x8*)&Ps[(wave * 16 + lm) * VPAD + kt * 32 + lq * 8];
#pragma unroll
      for (int jn = 0; jn < 4; ++jn) {
        const bf16x8 bV = *(const bf16x8*)&Vs[(jn * 16 + lm) * VPAD + kt * 32 + lq * 8];
        O[jn] = __builtin_amdgcn_mfma_f32_16x16x32_bf16(aP, bV, O[jn], 0, 0, 0);
      }
    }
  }

#pragma unroll
  for (int r = 0; r < 4; ++r) {
    const int q = q0 + wave * 16 + lq * 4 + r;
    const float inv = 1.0f / l_i[r];
#pragma unroll
    for (int jn = 0; jn < 4; ++jn) {
      const int d = jn * 16 + lm;
      ctx[(rowbase + q) * DMODEL + h * DHEAD + d] = (bf16_t)(O[jn][r] * inv);
    }
  }
}

// ---------- LayerNorm (row = 768) ----------
__global__ __launch_bounds__(256) void ln_kernel(const float* __restrict__ X,
                                                 const float* __restrict__ g,
                                                 const float* __restrict__ b,
                                                 bf16_t* __restrict__ outB,
                                                 float* __restrict__ outF) {
  const int row = blockIdx.x, tid = threadIdx.x;
  const float* xr = X + (long)row * DMODEL;
  const float v0 = xr[tid], v1 = xr[tid + 256], v2 = xr[tid + 512];
  __shared__ float r1[4], r2[4];
  const int wv = tid >> 6, ln = tid & 63;
  float s = wsum(v0 + v1 + v2);
  if (ln == 0) r1[wv] = s;
  __syncthreads();
  const float mean = (r1[0] + r1[1] + r1[2] + r1[3]) * (1.0f / DMODEL);
  const float d0 = v0 - mean, d1 = v1 - mean, d2 = v2 - mean;
  float q = wsum(d0 * d0 + d1 * d1 + d2 * d2);
  if (ln == 0) r2[wv] = q;
  __syncthreads();
  const float var = (r2[0] + r2[1] + r2[2] + r2[3]) * (1.0f / DMODEL);
  const float rs = rsqrtf(var + 1e-6f);
  const float y0 = d0 * rs * g[tid] + b[tid];
  const float y1 = d1 * rs * g[tid + 256] + b[tid + 256];
  const float y2 = d2 * rs * g[tid + 512] + b[tid + 512];
  const long base = (long)row * DMODEL;
  if (outB) {
    outB[base + tid] = (bf16_t)y0;
    outB[base + tid + 256] = (bf16_t)y1;
    outB[base + tid + 512] = (bf16_t)y2;
  }
  if (outF) {
    outF[base + tid] = y0;
    outF[base + tid + 256] = y1;
    outF[base + tid + 512] = y2;
  }
}

// ---------- reduce split-K partials + bias + residual, then LayerNorm ----------
__global__ __launch_bounds__(256) void reduce_ln_kernel(
    const float* __restrict__ parts, long pstr, int np,
    const float* __restrict__ bias, float* __restrict__ res,
    const float* __restrict__ g, const float* __restrict__ b,
    bf16_t* __restrict__ outB, float* __restrict__ outF) {
  const int row = blockIdx.x, tid = threadIdx.x;
  const long base = (long)row * DMODEL;
  float v0, v1, v2;
  {
    float t0 = res[base + tid] + bias[tid];
    float t1 = res[base + tid + 256] + bias[tid + 256];
    float t2 = res[base + tid + 512] + bias[tid + 512];
    for (int p = 0; p < np; ++p) {
      const float* pp = parts + p * pstr + base;
      t0 += pp[tid];
      t1 += pp[tid + 256];
      t2 += pp[tid + 512];
    }
    v0 = t0; v1 = t1; v2 = t2;
    res[base + tid] = t0;
    res[base + tid + 256] = t1;
    res[base + tid + 512] = t2;
  }
  __shared__ float r1[4], r2[4];
  const int wv = tid >> 6, ln = tid & 63;
  float s = wsum(v0 + v1 + v2);
  if (ln == 0) r1[wv] = s;
  __syncthreads();
  const float mean = (r1[0] + r1[1] + r1[2] + r1[3]) * (1.0f / DMODEL);
  const float d0 = v0 - mean, d1 = v1 - mean, d2 = v2 - mean;
  float q = wsum(d0 * d0 + d1 * d1 + d2 * d2);
  if (ln == 0) r2[wv] = q;
  __syncthreads();
  const float var = (r2[0] + r2[1] + r2[2] + r2[3]) * (1.0f / DMODEL);
  const float rs = rsqrtf(var + 1e-6f);
  const float y0 = d0 * rs * g[tid] + b[tid];
  const float y1 = d1 * rs * g[tid + 256] + b[tid + 256];
  const float y2 = d2 * rs * g[tid + 512] + b[tid + 512];
  if (outB) {
    outB[base + tid] = (bf16_t)y0;
    outB[base + tid + 256] = (bf16_t)y1;
    outB[base + tid + 512] = (bf16_t)y2;
  }
  if (outF) {
    outF[base + tid] = y0;
    outF[base + tid + 256] = y1;
    outF[base + tid + 512] = y2;
  }
}

// ---------- reduce split-K partials + bias -> strided bf16 (CA-q into qkv) ----------
__global__ __launch_bounds__(256) void reduce_cvtq_kernel(
    const float* __restrict__ parts, long pstr, int np,
    const float* __restrict__ bias, bf16_t* __restrict__ o) {
  const int row = blockIdx.x, tid = threadIdx.x;
  const long base = (long)row * DMODEL;
  const long ob = (long)row * 3 * DMODEL;
#pragma unroll
  for (int c = 0; c < 3; ++c) {
    const int col = tid + c * 256;
    float t = bias[col];
    for (int p = 0; p < np; ++p) t += parts[p * pstr + base + col];
    o[ob + col] = (bf16_t)t;
  }
}

// ---------- embedding * sqrt(D) + sinusoidal PE ----------
__global__ __launch_bounds__(256) void emb_kernel(const int* __restrict__ tgt,
                                                  const float* __restrict__ tab,
                                                  float* __restrict__ res) {
  const int row = blockIdx.x;
  const int t = row & (SEQ - 1);
  const long tok = tgt[row];
  const float* er = tab + tok * DMODEL;
  float* orow = res + (long)row * DMODEL;
  const float c1 = -9.210340371976184f / 768.0f;
  for (int c = threadIdx.x; c < DMODEL; c += 256) {
    const float e = er[c] * 27.712812921102035f;
    const float div = expf((float)(c & ~1) * c1);
    const float ang = (float)t * div;
    const float pe = (c & 1) ? cosf(ang) : sinf(ang);
    orow[c] = e + pe;
  }
}

// ---------- f32 -> bf16 convert (n4 = n/4) ----------
__global__ __launch_bounds__(256) void cvt_kernel(const float* __restrict__ in,
                                                  bf16_t* __restrict__ o, int n4) {
  const int i = blockIdx.x * 256 + threadIdx.x;
  if (i < n4) {
    const float4 v = ((const float4*)in)[i];
    bf16x4 r = {(bf16_t)v.x, (bf16_t)v.y, (bf16_t)v.z, (bf16_t)v.w};
    ((bf16x4*)o)[i] = r;
  }
}

// ---------- host ----------
extern "C" void kernel_launch(void* const* d_in, const int* in_sizes, int n_in,
                              void* d_out, int out_size, void* d_ws, size_t ws_size,
                              hipStream_t stream) {
  (void)in_sizes; (void)n_in; (void)out_size; (void)ws_size;
  const int* tgt = (const int*)d_in[0];
  const int* srct = (const int*)d_in[1];
  const float* memb = (const float*)d_in[2];
  const float* embt = (const float*)d_in[3];
  const float* sa_w = (const float*)d_in[4];
  const float* sa_b = (const float*)d_in[5];
  const float* ca_w = (const float*)d_in[6];
  const float* ca_b = (const float*)d_in[7];
  const float* ln_g = (const float*)d_in[8];
  const float* ln_b = (const float*)d_in[9];
  const float* ff_w1 = (const float*)d_in[10];
  const float* ff_b1 = (const float*)d_in[11];
  const float* ff_w2 = (const float*)d_in[12];
  const float* ff_b2 = (const float*)d_in[13];
  const float* out_g = (const float*)d_in[14];
  const float* out_b = (const float*)d_in[15];
  float* out = (float*)d_out;

  char* wsb = (char*)d_ws;
  size_t off = 0;
  auto alloc = [&](size_t bytes) -> void* {
    void* pp = wsb + off;
    off = (off + bytes + 255) & ~(size_t)255;
    return pp;
  };
  // NOTE: allocation ORDER and SIZES are load-bearing: FFN2 uses ksplit=4 and
  // its partials span parts(2*PSTR) + xb + qkvb exactly (both dead at that point).
  float* res = (float*)alloc((size_t)MROWS * DMODEL * 4);
  float* parts = (float*)alloc((size_t)2 * MROWS * DMODEL * 4);  // split-K partials 0..1
  bf16_t* xb = (bf16_t*)alloc((size_t)MROWS * DMODEL * 2);       // = parts[2] during FFN2
  bf16_t* qkvb = (bf16_t*)alloc((size_t)MROWS * 3 * DMODEL * 2); // = parts[3] during FFN2
  bf16_t* ctxb = (bf16_t*)alloc((size_t)MROWS * DMODEL * 2);
  bf16_t* membb = (bf16_t*)alloc((size_t)MROWS * DMODEL * 2);
  bf16_t* ffh = (bf16_t*)alloc((size_t)MROWS * DFFN * 2);
  bf16_t* wA = (bf16_t*)alloc((size_t)4 * DMODEL * DMODEL * 2);
  bf16_t* wF1 = (bf16_t*)alloc((size_t)DFFN * DMODEL * 2);
  bf16_t* wF2 = (bf16_t*)alloc((size_t)DFFN * DMODEL * 2);

  const long PSTR = (long)MROWS * DMODEL;

  // ts: 128 -> gemm128; 256 -> gemm256<var>
  auto gemm = [&](int ts, int var, const bf16_t* A, const bf16_t* Bm, const float* bias,
                  const float* resid, float* oF, bf16_t* oB, int M, int N, int K,
                  int lda, int ldb, int ldc, int act, int ksplit) {
    GP p{A, Bm, bias, resid, oF, oB, M, N, K, lda, ldb, ldc, PSTR, act, ksplit};
    if (ts == 256) {
      dim3 g((unsigned)(M / 256), (unsigned)(N / 256), (unsigned)ksplit);
      if (var == 0)
        gemm256<0><<<g, 512, 0, stream>>>(p);
      else
        gemm256<1><<<g, 512, 0, stream>>>(p);
    } else {
      dim3 g((unsigned)(M / 128), (unsigned)(N / 128), (unsigned)ksplit);
      gemm128<<<g, 256, 0, stream>>>(p);
    }
  };

  const long WSZ = (long)DMODEL * DMODEL;

  emb_kernel<<<MROWS, 256, 0, stream>>>(tgt, embt, res);
  cvt_kernel<<<(MROWS * DMODEL / 4 + 255) / 256, 256, 0, stream>>>(memb, membb,
                                                                   MROWS * DMODEL / 4);
  // ln1 output lives in ctxb (QKV input); xb stays dead across FFN2's aliased partials
  ln_kernel<<<MROWS, 256, 0, stream>>>(res, ln_g, ln_b, ctxb, nullptr);

  for (int l = 0; l < NLAYER; ++l) {
    const float* saw = sa_w + (long)l * 4 * WSZ;
    const float* sab = sa_b + (long)l * 4 * DMODEL;
    const float* caw = ca_w + (long)l * 4 * WSZ;
    const float* cab = ca_b + (long)l * 4 * DMODEL;

    // ======== self-attention ========   (ctxb = ln1(res))
    cvt_kernel<<<(int)((WSZ + 255) / 256), 256, 0, stream>>>(saw, wA, (int)WSZ);
    gemm(256, 1, ctxb, wA, sab, nullptr, nullptr, qkvb, MROWS, 3 * DMODEL, DMODEL,
         DMODEL, DMODEL, 3 * DMODEL, 0, 1);
    attn_kernel<<<dim3(SEQ / QT, BATCH * NHEAD), 256, 0, stream>>>(qkvb, tgt, ctxb, 1);
    gemm(128, 0, ctxb, wA + 3 * WSZ, nullptr, nullptr, parts, nullptr, MROWS, DMODEL,
         DMODEL, DMODEL, DMODEL, DMODEL, 0, 2);
    reduce_ln_kernel<<<MROWS, 256, 0, stream>>>(parts, PSTR, 2, sab + 3 * DMODEL, res,
                                                ln_g + (l * 3 + 1) * DMODEL,
                                                ln_b + (l * 3 + 1) * DMODEL, xb, nullptr);

    // ======== cross-attention ========  (xb = ln2)
    cvt_kernel<<<(int)((WSZ + 255) / 256), 256, 0, stream>>>(caw, wA, (int)WSZ);
    gemm(128, 0, xb, wA, nullptr, nullptr, parts, nullptr, MROWS, DMODEL, DMODEL,
         DMODEL, DMODEL, DMODEL, 0, 2);
    reduce_cvtq_kernel<<<MROWS, 256, 0, stream>>>(parts, PSTR, 2, cab, qkvb);
    gemm(128, 0, membb, wA + WSZ, cab + DMODEL, nullptr, nullptr, qkvb + DMODEL, MROWS,
         2 * DMODEL, DMODEL, DMODEL, DMODEL, 3 * DMODEL, 0, 1);
    attn_kernel<<<dim3(SEQ / QT, BATCH * NHEAD), 256, 0, stream>>>(qkvb, srct, ctxb, 0);
    gemm(128, 0, ctxb, wA + 3 * WSZ, nullptr, nullptr, parts, nullptr, MROWS, DMODEL,
         DMODEL, DMODEL, DMODEL, DMODEL, 0, 2);
    reduce_ln_kernel<<<MROWS, 256, 0, stream>>>(parts, PSTR, 2, cab + 3 * DMODEL, res,
                                                ln_g + (l * 3 + 2) * DMODEL,
                                                ln_b + (l * 3 + 2) * DMODEL, xb, nullptr);

    // ======== FFN ========  (xb = ln3)
    cvt_kernel<<<(int)((DFFN * (long)DMODEL / 4 + 255) / 256), 256, 0, stream>>>(
        ff_w1 + (long)l * DFFN * DMODEL, wF1, (int)(DFFN * (long)DMODEL / 4));
    cvt_kernel<<<(int)((DFFN * (long)DMODEL / 4 + 255) / 256), 256, 0, stream>>>(
        ff_w2 + (long)l * DFFN * DMODEL, wF2, (int)(DFFN * (long)DMODEL / 4));
    gemm(256, 1, xb, wF1, ff_b1 + (long)l * DFFN, nullptr, nullptr, ffh, MROWS, DFFN,
         DMODEL, DMODEL, DMODEL, DFFN, 1, 1);
    // ksplit=4: partials 2,3 alias xb/qkvb (dead here); reduce writes ln1 -> ctxb
    gemm(256, 0, ffh, wF2, nullptr, nullptr, parts, nullptr, MROWS, DMODEL, DFFN,
         DFFN, DFFN, DMODEL, 0, 4);
    if (l < NLAYER - 1) {
      reduce_ln_kernel<<<MROWS, 256, 0, stream>>>(parts, PSTR, 4, ff_b2 + (long)l * DMODEL,
                                                  res, ln_g + ((l + 1) * 3) * DMODEL,
                                                  ln_b + ((l + 1) * 3) * DMODEL, ctxb, nullptr);
    } else {
      reduce_ln_kernel<<<MROWS, 256, 0, stream>>>(parts, PSTR, 4, ff_b2 + (long)l * DMODEL,
                                                  res, out_g, out_b, nullptr, out);
    }
  }
}